// Round 3
// baseline (146.087 us; speedup 1.0000x reference)
//
#include <hip/hip_runtime.h>

// CenterLoss: out = mean_i ||x_i - centers[labels_i]||^2
// B=16384, D=512, C=4000.
// Single fused kernel: one 64-lane wave per 2 consecutive rows (all 8 float4
// loads in flight), per-block partial to d_ws, last-block-done reduction
// (threadfence + device-scope counter atomic) writes the mean. Eliminates
// the second launch + tail from round 2.
// Round-1 lesson: 4096 same-address fp atomics serialized at ~14ns each
// (56us); a single completion *counter* atomic per block (2048 total,
// overlapped with streaming) is fine.

#define B_SIZE 16384
#define D_SIZE 512
#define S1_BLOCKS 2048   // 2048 blocks * 4 waves * 2 rows = 16384 rows

// d_ws layout: [0] counter (uint), [64 .. 64+2048) partials (float)
#define PARTIALS_OFF 64

__global__ __launch_bounds__(256) void center_loss_fused(
    const float* __restrict__ x,
    const int* __restrict__ labels,
    const float* __restrict__ centers,
    float* __restrict__ ws,
    float* __restrict__ out) {

    unsigned int* counter = reinterpret_cast<unsigned int*>(ws);
    float* partials = ws + PARTIALS_OFF;

    const int lane = threadIdx.x & 63;
    const int wave = threadIdx.x >> 6;                 // 4 waves per block
    const int gw   = (blockIdx.x << 2) + wave;         // global wave id
    const int row0 = gw << 1;                          // 2 consecutive rows per wave
    const int row1 = row0 + 1;

    const int l0 = labels[row0];
    const int l1 = labels[row1];

    const float4* x0 = reinterpret_cast<const float4*>(x + (size_t)row0 * D_SIZE) + (lane << 1);
    const float4* x1 = reinterpret_cast<const float4*>(x + (size_t)row1 * D_SIZE) + (lane << 1);
    const float4* c0 = reinterpret_cast<const float4*>(centers + (size_t)l0 * D_SIZE) + (lane << 1);
    const float4* c1 = reinterpret_cast<const float4*>(centers + (size_t)l1 * D_SIZE) + (lane << 1);

    // issue all 8 loads before any use
    float4 xa0 = x0[0], xb0 = x0[1];
    float4 xa1 = x1[0], xb1 = x1[1];
    float4 ca0 = c0[0], cb0 = c0[1];
    float4 ca1 = c1[0], cb1 = c1[1];

    float acc = 0.0f, d;
    d = xa0.x - ca0.x; acc += d * d;
    d = xa0.y - ca0.y; acc += d * d;
    d = xa0.z - ca0.z; acc += d * d;
    d = xa0.w - ca0.w; acc += d * d;
    d = xb0.x - cb0.x; acc += d * d;
    d = xb0.y - cb0.y; acc += d * d;
    d = xb0.z - cb0.z; acc += d * d;
    d = xb0.w - cb0.w; acc += d * d;
    d = xa1.x - ca1.x; acc += d * d;
    d = xa1.y - ca1.y; acc += d * d;
    d = xa1.z - ca1.z; acc += d * d;
    d = xa1.w - ca1.w; acc += d * d;
    d = xb1.x - cb1.x; acc += d * d;
    d = xb1.y - cb1.y; acc += d * d;
    d = xb1.z - cb1.z; acc += d * d;
    d = xb1.w - cb1.w; acc += d * d;

    // wave-level reduction over 64 lanes
    #pragma unroll
    for (int off = 32; off > 0; off >>= 1)
        acc += __shfl_down(acc, off, 64);

    __shared__ float partial[4];
    __shared__ bool is_last;
    if (lane == 0) partial[wave] = acc;
    __syncthreads();

    if (threadIdx.x == 0) {
        partials[blockIdx.x] = partial[0] + partial[1] + partial[2] + partial[3];
        __threadfence();  // make partial visible device-wide before signaling
        unsigned int prev = atomicAdd(counter, 1u);
        is_last = (prev == S1_BLOCKS - 1);
    }
    __syncthreads();

    if (is_last) {
        // 256 threads reduce 2048 partials (8 each)
        const int t = threadIdx.x;
        float s = 0.0f;
        #pragma unroll
        for (int k = 0; k < 8; ++k)
            s += partials[t + (k << 8)];

        #pragma unroll
        for (int off = 32; off > 0; off >>= 1)
            s += __shfl_down(s, off, 64);

        __shared__ float fin[4];
        if (lane == 0) fin[wave] = s;
        __syncthreads();
        if (t == 0)
            out[0] = (fin[0] + fin[1] + fin[2] + fin[3]) * (1.0f / (float)B_SIZE);
    }
}

extern "C" void kernel_launch(void* const* d_in, const int* in_sizes, int n_in,
                              void* d_out, int out_size, void* d_ws, size_t ws_size,
                              hipStream_t stream) {
    const float* x       = (const float*)d_in[0];
    const int*   labels  = (const int*)d_in[1];
    const float* centers = (const float*)d_in[2];
    float* out = (float*)d_out;
    float* ws  = (float*)d_ws;

    // zero the completion counter (d_ws is re-poisoned to 0xAA each replay)
    hipMemsetAsync(d_ws, 0, 4, stream);

    center_loss_fused<<<S1_BLOCKS, 256, 0, stream>>>(x, labels, centers, ws, out);
}

// Round 5
// 87.738 us; speedup vs baseline: 1.6650x; 1.6650x over previous
//
#include <hip/hip_runtime.h>

// CenterLoss: out = mean_i ||x_i - centers[labels_i]||^2
// B=16384, D=512, C=4000.
//
// Round-2 proven structure (83.3us total, ~10us controllable):
//   Stage 1: one 64-lane wave per 2 consecutive rows, 8 16B loads in
//            flight, per-block partial to d_ws. No atomics, no fences.
//   Stage 2: one 256-thread block reduces 2048 partials -> mean -> d_out.
//
// Round-1 lesson: 4096 same-address fp atomics serialize (~14ns each, 56us).
// Round-3 lesson: last-block-done + __threadfence() is WORSE (94us @ 300GB/s):
//   device-scope release on multi-XCD CDNA4 = L2 writeback per block, x2048.
// Round-4 lesson: __builtin_nontemporal_load needs a NATIVE vector type
//   (ext_vector_type), not HIP's float4 class.
// Remaining dur_us is ~73us fixed harness overhead (256MB ws re-poison +
// input restores inside the timed region) + ~8us here.

#define B_SIZE 16384
#define D_SIZE 512
#define S1_BLOCKS 2048   // 2048 blocks * 4 waves * 2 rows = 16384 rows

typedef float vfloat4 __attribute__((ext_vector_type(4)));

__device__ __forceinline__ vfloat4 nt_load4(const float* p) {
    return __builtin_nontemporal_load(reinterpret_cast<const vfloat4*>(p));
}

__global__ __launch_bounds__(256) void center_loss_stage1(
    const float* __restrict__ x,
    const int* __restrict__ labels,
    const float* __restrict__ centers,
    float* __restrict__ partials) {

    const int lane = threadIdx.x & 63;
    const int wave = threadIdx.x >> 6;                 // 4 waves per block
    const int gw   = (blockIdx.x << 2) + wave;         // global wave id
    const int row0 = gw << 1;                          // 2 consecutive rows per wave
    const int row1 = row0 + 1;

    const int l0 = labels[row0];
    const int l1 = labels[row1];

    const float* x0 = x + (size_t)row0 * D_SIZE + (lane << 3);
    const float* x1 = x + (size_t)row1 * D_SIZE + (lane << 3);
    const vfloat4* c0 = reinterpret_cast<const vfloat4*>(centers + (size_t)l0 * D_SIZE) + (lane << 1);
    const vfloat4* c1 = reinterpret_cast<const vfloat4*>(centers + (size_t)l1 * D_SIZE) + (lane << 1);

    // issue all 8 loads before any use; x is streamed once -> nontemporal
    // (don't evict the 8MB centers table from L2)
    vfloat4 xa0 = nt_load4(x0), xb0 = nt_load4(x0 + 4);
    vfloat4 xa1 = nt_load4(x1), xb1 = nt_load4(x1 + 4);
    vfloat4 ca0 = c0[0], cb0 = c0[1];
    vfloat4 ca1 = c1[0], cb1 = c1[1];

    vfloat4 d0 = xa0 - ca0;
    vfloat4 d1 = xb0 - cb0;
    vfloat4 d2 = xa1 - ca1;
    vfloat4 d3 = xb1 - cb1;

    float acc = 0.0f;
    acc += d0.x * d0.x + d0.y * d0.y + d0.z * d0.z + d0.w * d0.w;
    acc += d1.x * d1.x + d1.y * d1.y + d1.z * d1.z + d1.w * d1.w;
    acc += d2.x * d2.x + d2.y * d2.y + d2.z * d2.z + d2.w * d2.w;
    acc += d3.x * d3.x + d3.y * d3.y + d3.z * d3.z + d3.w * d3.w;

    // wave-level reduction over 64 lanes
    #pragma unroll
    for (int off = 32; off > 0; off >>= 1)
        acc += __shfl_down(acc, off, 64);

    __shared__ float partial[4];
    if (lane == 0) partial[wave] = acc;
    __syncthreads();

    if (threadIdx.x == 0)
        partials[blockIdx.x] = partial[0] + partial[1] + partial[2] + partial[3];
}

__global__ __launch_bounds__(256) void center_loss_stage2(
    const float* __restrict__ partials,
    float* __restrict__ out) {

    const int t = threadIdx.x;
    float acc = 0.0f;
    #pragma unroll
    for (int k = 0; k < 8; ++k)
        acc += partials[t + (k << 8)];

    const int lane = t & 63;
    const int wave = t >> 6;   // 4 waves

    #pragma unroll
    for (int off = 32; off > 0; off >>= 1)
        acc += __shfl_down(acc, off, 64);

    __shared__ float partial[4];
    if (lane == 0) partial[wave] = acc;
    __syncthreads();

    if (t == 0)
        out[0] = (partial[0] + partial[1] + partial[2] + partial[3])
                 * (1.0f / (float)B_SIZE);
}

extern "C" void kernel_launch(void* const* d_in, const int* in_sizes, int n_in,
                              void* d_out, int out_size, void* d_ws, size_t ws_size,
                              hipStream_t stream) {
    const float* x       = (const float*)d_in[0];
    const int*   labels  = (const int*)d_in[1];
    const float* centers = (const float*)d_in[2];
    float* out      = (float*)d_out;
    float* partials = (float*)d_ws;   // 2048 floats = 8 KB scratch

    center_loss_stage1<<<S1_BLOCKS, 256, 0, stream>>>(x, labels, centers, partials);
    center_loss_stage2<<<1, 256, 0, stream>>>(partials, out);
}

// Round 6
// 83.983 us; speedup vs baseline: 1.7395x; 1.0447x over previous
//
#include <hip/hip_runtime.h>

// CenterLoss: out = mean_i ||x_i - centers[labels_i]||^2
// B=16384, D=512, C=4000.
//
// Final structure (round-2 proven, 83.3us total; ~73us is fixed harness
// overhead — 256MB ws re-poison + input restores — visible as
// fillBufferAligned dispatches at ~43us in every profile):
//   Stage 1: one 64-lane wave per 2 consecutive rows, 8 16B cached loads in
//            flight, per-block partial to d_ws. No atomics, no fences.
//   Stage 2: one 256-thread block reduces 2048 partials -> mean -> d_out.
//
// Lessons:
//  R1: 4096 same-address fp atomics serialize (~14ns each) -> 56us kernel.
//  R3: last-block-done + __threadfence() is worse (94us @ 300GB/s): device
//      release on multi-XCD CDNA4 forces per-block L2 writeback, x2048.
//  R5: nontemporal x loads REGRESS (+4us): harness restores inputs right
//      before each replay, so x/centers are L3-warm; nt bypasses that.

#define B_SIZE 16384
#define D_SIZE 512
#define S1_BLOCKS 2048   // 2048 blocks * 4 waves * 2 rows = 16384 rows

__global__ __launch_bounds__(256) void center_loss_stage1(
    const float* __restrict__ x,
    const int* __restrict__ labels,
    const float* __restrict__ centers,
    float* __restrict__ partials) {

    const int lane = threadIdx.x & 63;
    const int wave = threadIdx.x >> 6;                 // 4 waves per block
    const int gw   = (blockIdx.x << 2) + wave;         // global wave id
    const int row0 = gw << 1;                          // 2 consecutive rows per wave
    const int row1 = row0 + 1;

    const int l0 = labels[row0];
    const int l1 = labels[row1];

    const float4* x0 = reinterpret_cast<const float4*>(x + (size_t)row0 * D_SIZE) + (lane << 1);
    const float4* x1 = reinterpret_cast<const float4*>(x + (size_t)row1 * D_SIZE) + (lane << 1);
    const float4* c0 = reinterpret_cast<const float4*>(centers + (size_t)l0 * D_SIZE) + (lane << 1);
    const float4* c1 = reinterpret_cast<const float4*>(centers + (size_t)l1 * D_SIZE) + (lane << 1);

    // issue all 8 loads before any use
    float4 xa0 = x0[0], xb0 = x0[1];
    float4 xa1 = x1[0], xb1 = x1[1];
    float4 ca0 = c0[0], cb0 = c0[1];
    float4 ca1 = c1[0], cb1 = c1[1];

    float acc = 0.0f, d;
    d = xa0.x - ca0.x; acc += d * d;
    d = xa0.y - ca0.y; acc += d * d;
    d = xa0.z - ca0.z; acc += d * d;
    d = xa0.w - ca0.w; acc += d * d;
    d = xb0.x - cb0.x; acc += d * d;
    d = xb0.y - cb0.y; acc += d * d;
    d = xb0.z - cb0.z; acc += d * d;
    d = xb0.w - cb0.w; acc += d * d;
    d = xa1.x - ca1.x; acc += d * d;
    d = xa1.y - ca1.y; acc += d * d;
    d = xa1.z - ca1.z; acc += d * d;
    d = xa1.w - ca1.w; acc += d * d;
    d = xb1.x - cb1.x; acc += d * d;
    d = xb1.y - cb1.y; acc += d * d;
    d = xb1.z - cb1.z; acc += d * d;
    d = xb1.w - cb1.w; acc += d * d;

    // wave-level reduction over 64 lanes
    #pragma unroll
    for (int off = 32; off > 0; off >>= 1)
        acc += __shfl_down(acc, off, 64);

    __shared__ float partial[4];
    if (lane == 0) partial[wave] = acc;
    __syncthreads();

    if (threadIdx.x == 0)
        partials[blockIdx.x] = partial[0] + partial[1] + partial[2] + partial[3];
}

__global__ __launch_bounds__(256) void center_loss_stage2(
    const float* __restrict__ partials,
    float* __restrict__ out) {

    const int t = threadIdx.x;
    float acc = 0.0f;
    #pragma unroll
    for (int k = 0; k < 8; ++k)
        acc += partials[t + (k << 8)];

    const int lane = t & 63;
    const int wave = t >> 6;   // 4 waves

    #pragma unroll
    for (int off = 32; off > 0; off >>= 1)
        acc += __shfl_down(acc, off, 64);

    __shared__ float partial[4];
    if (lane == 0) partial[wave] = acc;
    __syncthreads();

    if (t == 0)
        out[0] = (partial[0] + partial[1] + partial[2] + partial[3])
                 * (1.0f / (float)B_SIZE);
}

extern "C" void kernel_launch(void* const* d_in, const int* in_sizes, int n_in,
                              void* d_out, int out_size, void* d_ws, size_t ws_size,
                              hipStream_t stream) {
    const float* x       = (const float*)d_in[0];
    const int*   labels  = (const int*)d_in[1];
    const float* centers = (const float*)d_in[2];
    float* out      = (float*)d_out;
    float* partials = (float*)d_ws;   // 2048 floats = 8 KB scratch

    center_loss_stage1<<<S1_BLOCKS, 256, 0, stream>>>(x, labels, centers, partials);
    center_loss_stage2<<<1, 256, 0, stream>>>(partials, out);
}